// Round 11
// baseline (184.072 us; speedup 1.0000x reference)
//
#include <hip/hip_runtime.h>
#include <hip/hip_bf16.h>

#define HIDDEN 1024
#define SEQ 2048
#define NH 16

typedef float f32x4 __attribute__((ext_vector_type(4)));
typedef __bf16 bf16x8 __attribute__((ext_vector_type(8)));

typedef __attribute__((address_space(1))) unsigned int gu32;
typedef __attribute__((address_space(3))) unsigned int lu32;

__device__ __forceinline__ unsigned short f2bf(float f) {
  union { float f; unsigned u; } v; v.f = f;
  unsigned u = v.u;
  u = (u + 0x7fffu + ((u >> 16) & 1u)) >> 16;
  return (unsigned short)u;
}

__device__ __forceinline__ void gload16(const unsigned short* g, unsigned short* l) {
  __builtin_amdgcn_global_load_lds((gu32*)(void*)g, (lu32*)(void*)l, 16, 0, 0);
}

__device__ __forceinline__ f32x4 mfma32(bf16x8 a, bf16x8 b, f32x4 c) {
  return __builtin_amdgcn_mfma_f32_16x16x32_bf16(a, b, c, 0, 0, 0);
}

// Schraudolph in bf16 domain: bits(2^s) ~= trunc(s*128 + 16250.99), err +-3%
__device__ __forceinline__ unsigned sch(float s) {
  return (unsigned)(int)fmaf(s, 128.0f, 16250.99f);
}

// ---------------- fused prep: cast X->bf16 ; transpose both weights ---------
__global__ __launch_bounds__(256) void k_prep(const float* __restrict__ hs,
                                              unsigned short* __restrict__ Xb,
                                              const float* __restrict__ w_qkv,
                                              unsigned short* __restrict__ Wqt,
                                              const float* __restrict__ w_dense,
                                              unsigned short* __restrict__ Wdt) {
  __shared__ unsigned short t[32][33];
  const int bid = blockIdx.x;
  if (bid < 4096) {
    int i = bid * 256 + threadIdx.x;
    float4 v = ((const float4*)hs)[i];
    ushort4 r;
    r.x = f2bf(v.x); r.y = f2bf(v.y); r.z = f2bf(v.z); r.w = f2bf(v.w);
    ((ushort4*)Xb)[i] = r;
    return;
  }
  const float* W; unsigned short* Wt; int N, n0, k0;
  if (bid < 4096 + 3072) {
    int b2 = bid - 4096;
    W = w_qkv; Wt = Wqt; N = 3072;
    n0 = (b2 % 96) * 32; k0 = (b2 / 96) * 32;
  } else {
    int b3 = bid - 7168;
    W = w_dense; Wt = Wdt; N = 1024;
    n0 = (b3 % 32) * 32; k0 = (b3 / 32) * 32;
  }
  const int K = 1024;
  int tx = threadIdx.x & 31, ty = threadIdx.x >> 5;
  #pragma unroll
  for (int i = ty; i < 32; i += 8)
    t[i][tx] = f2bf(W[(size_t)(k0 + i) * N + n0 + tx]);
  __syncthreads();
  #pragma unroll
  for (int i = ty; i < 32; i += 8)
    Wt[(size_t)(n0 + i) * K + k0 + tx] = t[tx][i];
}

// ---------------- QKV GEMM: X[4096,1024] @ Wqt[3072,1024]^T -----------------
// Epilogue: Qg/Kg [bh][seq][64] (Q pre-scaled by log2e/8);
// Vg [bh][64][2048]: per 128-key tile, slot = bphys*8 + h*4 + r with
// bphys = (c*4+quad)^(d&7) — XOR bank swizzle matching attn's DMA-staged V.
__global__ __launch_bounds__(256, 4) void k_gemm_qkv(
    const unsigned short* __restrict__ A, const unsigned short* __restrict__ Bt,
    const float* __restrict__ bias, unsigned short* __restrict__ Qg,
    unsigned short* __restrict__ Kg, unsigned short* __restrict__ Vg) {
  __shared__ unsigned short As0[128 * 32], As1[128 * 32];
  __shared__ unsigned short Bs0[128 * 32], Bs1[128 * 32];
  const int K = 1024;
  const int tid = threadIdx.x;
  const int lane = tid & 63;
  const int wave = tid >> 6;
  const int wm = wave >> 1, wn = wave & 1;
  const int quad = lane >> 4, l16 = lane & 15;
  const int srow = lane >> 2, scol = (lane & 3) << 3;
  const int bm = blockIdx.y * 128, bn = blockIdx.x * 128;

  f32x4 acc[4][4] = {};

  const unsigned short* gA = A + (size_t)(bm + wave * 16 + srow) * K + scol;
  const unsigned short* gA2 = gA + (size_t)64 * K;
  const unsigned short* gB = Bt + (size_t)(bn + wave * 16 + srow) * K + scol;
  const unsigned short* gB2 = gB + (size_t)64 * K;
  unsigned short* lA0 = &As0[wave * 512];
  unsigned short* lA0b = &As0[(wave + 4) * 512];
  unsigned short* lA1 = &As1[wave * 512];
  unsigned short* lA1b = &As1[(wave + 4) * 512];
  unsigned short* lB0 = &Bs0[wave * 512];
  unsigned short* lB0b = &Bs0[(wave + 4) * 512];
  unsigned short* lB1 = &Bs1[wave * 512];
  unsigned short* lB1b = &Bs1[(wave + 4) * 512];

  for (int k0 = 0; k0 < K; k0 += 64) {
    gload16(gA + k0, lA0);
    gload16(gA2 + k0, lA0b);
    gload16(gA + k0 + 32, lA1);
    gload16(gA2 + k0 + 32, lA1b);
    gload16(gB + k0, lB0);
    gload16(gB2 + k0, lB0b);
    gload16(gB + k0 + 32, lB1);
    gload16(gB2 + k0 + 32, lB1b);
    __syncthreads();
    #pragma unroll
    for (int ph = 0; ph < 2; ph++) {
      const unsigned short* Ap = ph ? As1 : As0;
      const unsigned short* Bp = ph ? Bs1 : Bs0;
      bf16x8 af[4], bfr[4];
      #pragma unroll
      for (int i = 0; i < 4; i++)
        af[i] = *(const bf16x8*)&Ap[(wm * 64 + i * 16 + l16) * 32 + quad * 8];
      #pragma unroll
      for (int i = 0; i < 4; i++)
        bfr[i] = *(const bf16x8*)&Bp[(wn * 64 + i * 16 + l16) * 32 + quad * 8];
      #pragma unroll
      for (int mi = 0; mi < 4; mi++)
        #pragma unroll
        for (int ni = 0; ni < 4; ni++)
          acc[mi][ni] = mfma32(af[mi], bfr[ni], acc[mi][ni]);
    }
    __syncthreads();
  }

  const int b = bm >> 11;
  const int qb = bm & 2047;
  const float c2 = 0.18033688011112042f;  // log2(e)/sqrt(64)
  #pragma unroll
  for (int ni = 0; ni < 4; ni++) {
    const int cs = bn + wn * 64 + ni * 16;
    const int head = cs / 192;
    const int which = (cs % 192) >> 6;
    const int d = (cs & 63) + l16;
    const int bh = b * 16 + head;
    const float bv = bias[cs + l16];
    if (which == 2) {
      const int swz = l16 & 7;
      #pragma unroll
      for (int cp = 0; cp < 2; cp++) {
        unsigned short pk[8];
        #pragma unroll
        for (int hh = 0; hh < 2; hh++)
          #pragma unroll
          for (int r = 0; r < 4; r++)
            pk[hh * 4 + r] = f2bf(acc[cp * 2 + hh][ni][r] + bv);
        const int cgrp = wm * 2 + cp;
        const int bphys = (cgrp * 4 + quad) ^ swz;
        unsigned short* vp = &Vg[((size_t)bh * 64 + d) * SEQ + qb + bphys * 8];
        *(uint4*)vp = *(const uint4*)pk;
      }
    } else if (which == 0) {
      #pragma unroll
      for (int mi = 0; mi < 4; mi++) {
        const int q0r = qb + wm * 64 + mi * 16 + quad * 4;
        #pragma unroll
        for (int r = 0; r < 4; r++)
          Qg[((size_t)bh * SEQ + q0r + r) * 64 + d] =
              f2bf((acc[mi][ni][r] + bv) * c2);
      }
    } else {
      #pragma unroll
      for (int mi = 0; mi < 4; mi++) {
        const int q0r = qb + wm * 64 + mi * 16 + quad * 4;
        #pragma unroll
        for (int r = 0; r < 4; r++)
          Kg[((size_t)bh * SEQ + q0r + r) * 64 + d] = f2bf(acc[mi][ni][r] + bv);
      }
    }
  }
}

// ---------------- flash attention: no split-K, double-buffered staging ------
// 512 blocks (2/CU), 64 KB LDS (2 buffers x (K 16KB + V 16KB)). Loop shape:
// barrier -> issue DMA for tile t+1 into buffer B -> compute tile t from A.
// The compiler's vmcnt(0)-before-barrier then waits on loads that had a full
// compute phase to land (the R10 structure drained them cold at 2 blocks/CU).
__global__ __launch_bounds__(256, 2) void k_attn(const unsigned short* __restrict__ Qg,
                                                 const unsigned short* __restrict__ Kg,
                                                 const unsigned short* __restrict__ Vg,
                                                 unsigned short* __restrict__ ctx) {
  __shared__ unsigned short Ks0[2][128 * 32];
  __shared__ unsigned short Ks1[2][128 * 32];
  __shared__ unsigned short Vs[2][64 * 128];  // [d][slot], NO pad (DMA target)
  const int tid = threadIdx.x, lane = tid & 63, wave = tid >> 6;
  const int quad = lane >> 4, l16 = lane & 15;
  const int srow = lane >> 2, scol = (lane & 3) << 3;
  const int bid = blockIdx.x;
  const int bh = bid & 31;
  const int qblk = bid >> 5;          // 0..15
  const int q0 = qblk * 128 + wave * 32;
  const int swz = l16 & 7;

  bf16x8 Qf[2][2];
  #pragma unroll
  for (int qt = 0; qt < 2; qt++)
    #pragma unroll
    for (int kh = 0; kh < 2; kh++)
      Qf[qt][kh] = *(const bf16x8*)(Qg + ((size_t)bh * SEQ + q0 + qt * 16 + l16) * 64 +
                                    kh * 32 + quad * 8);

  f32x4 o[2][4] = {};
  f32x4 ol[2] = {};
  union { short s[8]; bf16x8 v; } ones8u;
  #pragma unroll
  for (int i = 0; i < 8; i++) ones8u.s[i] = 16256;  // bf16 1.0
  const bf16x8 ones8 = ones8u.v;

  const int vr = lane >> 4;
  const unsigned short* gKbase =
      Kg + ((size_t)bh * SEQ + wave * 16 + srow) * 64 + scol;
  const unsigned short* gVlane =
      Vg + ((size_t)bh * 64 + wave * 16 + vr) * SEQ + (lane & 15) * 8;

  // prologue: stage tile 0 into buffer 0
  {
    const unsigned short* gK = gKbase;
    gload16(gK, &Ks0[0][wave * 512]);
    gload16(gK + 32, &Ks1[0][wave * 512]);
    const unsigned short* gK2 = gK + (size_t)64 * 64;
    gload16(gK2, &Ks0[0][2048 + wave * 512]);
    gload16(gK2 + 32, &Ks1[0][2048 + wave * 512]);
    #pragma unroll
    for (int c = 0; c < 4; c++)
      gload16(gVlane + (size_t)(c * 4) * SEQ, &Vs[0][(wave * 16 + c * 4) * 128]);
  }

  for (int t = 0; t < 16; t++) {
    const int buf = t & 1;
    __syncthreads();  // waits (vmcnt 0) for loads into `buf` + all waves synced

    // issue DMA for tile t+1 into the other buffer (covered by compute below)
    if (t + 1 < 16) {
      const int nb = buf ^ 1;
      const int k1 = (t + 1) * 128;
      const unsigned short* gK = gKbase + (size_t)k1 * 64;
      gload16(gK, &Ks0[nb][wave * 512]);
      gload16(gK + 32, &Ks1[nb][wave * 512]);
      const unsigned short* gK2 = gK + (size_t)64 * 64;
      gload16(gK2, &Ks0[nb][2048 + wave * 512]);
      gload16(gK2 + 32, &Ks1[nb][2048 + wave * 512]);
      #pragma unroll
      for (int c = 0; c < 4; c++)
        gload16(gVlane + (size_t)(c * 4) * SEQ + k1,
                &Vs[nb][(wave * 16 + c * 4) * 128]);
    }

    // S^T = K*Q^T per 16-key tile; Schraudolph-pack P dwords
    unsigned pu[2][8][2];
    #pragma unroll
    for (int nt = 0; nt < 8; nt++) {
      bf16x8 a0 = *(const bf16x8*)&Ks0[buf][(nt * 16 + l16) * 32 + quad * 8];
      bf16x8 a1 = *(const bf16x8*)&Ks1[buf][(nt * 16 + l16) * 32 + quad * 8];
      #pragma unroll
      for (int qt = 0; qt < 2; qt++) {
        f32x4 s = {0.f, 0.f, 0.f, 0.f};
        s = mfma32(a0, Qf[qt][0], s);
        s = mfma32(a1, Qf[qt][1], s);
        pu[qt][nt][0] = __builtin_amdgcn_perm(sch(s[1]), sch(s[0]), 0x05040100u);
        pu[qt][nt][1] = __builtin_amdgcn_perm(sch(s[3]), sch(s[2]), 0x05040100u);
      }
    }
    // O += P*V ; l += P*1  (x32; V b128 with XOR de-swizzle)
    #pragma unroll
    for (int c = 0; c < 4; c++) {
      union { unsigned u[4]; bf16x8 v; } PA0, PA1;
      PA0.u[0] = pu[0][2 * c][0];     PA0.u[1] = pu[0][2 * c][1];
      PA0.u[2] = pu[0][2 * c + 1][0]; PA0.u[3] = pu[0][2 * c + 1][1];
      PA1.u[0] = pu[1][2 * c][0];     PA1.u[1] = pu[1][2 * c][1];
      PA1.u[2] = pu[1][2 * c + 1][0]; PA1.u[3] = pu[1][2 * c + 1][1];
      const int bp = ((c * 4 + quad) ^ swz) * 8;
      #pragma unroll
      for (int nd = 0; nd < 4; nd++) {
        bf16x8 vb = *(const bf16x8*)&Vs[buf][(nd * 16 + l16) * 128 + bp];
        o[0][nd] = mfma32(PA0.v, vb, o[0][nd]);
        o[1][nd] = mfma32(PA1.v, vb, o[1][nd]);
      }
      ol[0] = mfma32(PA0.v, ones8, ol[0]);
      ol[1] = mfma32(PA1.v, ones8, ol[1]);
    }
  }

  // epilogue: normalize (ol[qt][r] is the full row-sum for the same row as
  // o[qt][*][r]) and write ctx directly
  const int b = bh >> 4, h = bh & 15;
  #pragma unroll
  for (int qt = 0; qt < 2; qt++) {
    #pragma unroll
    for (int r = 0; r < 4; r++) {
      float il = 1.0f / ol[qt][r];
      int q = q0 + qt * 16 + quad * 4 + r;
      #pragma unroll
      for (int nd = 0; nd < 4; nd++)
        ctx[((size_t)b * SEQ + q) * HIDDEN + h * 64 + nd * 16 + l16] =
            f2bf(o[qt][nd][r] * il);
    }
  }
}

// ---------------- dense GEMM 128x64-tile, BK=64 dual-panel ------------------
__global__ __launch_bounds__(256, 4) void k_gemm_dense(
    const unsigned short* __restrict__ A, const unsigned short* __restrict__ Bt,
    const float* __restrict__ bias, const float* __restrict__ res,
    float* __restrict__ Cf) {
  __shared__ unsigned short As0[128 * 32], As1[128 * 32];
  __shared__ unsigned short Bs0[64 * 32], Bs1[64 * 32];
  const int K = 1024, N = 1024;
  const int tid = threadIdx.x, lane = tid & 63, wave = tid >> 6;
  const int quad = lane >> 4, l16 = lane & 15;
  const int srow = lane >> 2, scol = (lane & 3) << 3;
  const int bm = blockIdx.y * 128, bn = blockIdx.x * 64;

  f32x4 acc[2][4] = {};
  const unsigned short* gA = A + (size_t)(bm + wave * 16 + srow) * K + scol;
  const unsigned short* gA2 = gA + (size_t)64 * K;
  const unsigned short* gB = Bt + (size_t)(bn + wave * 16 + srow) * K + scol;
  unsigned short* lA0 = &As0[wave * 512];
  unsigned short* lA0b = &As0[(wave + 4) * 512];
  unsigned short* lA1 = &As1[wave * 512];
  unsigned short* lA1b = &As1[(wave + 4) * 512];
  unsigned short* lB0 = &Bs0[wave * 512];
  unsigned short* lB1 = &Bs1[wave * 512];

  for (int k0 = 0; k0 < K; k0 += 64) {
    gload16(gA + k0, lA0);
    gload16(gA2 + k0, lA0b);
    gload16(gA + k0 + 32, lA1);
    gload16(gA2 + k0 + 32, lA1b);
    gload16(gB + k0, lB0);
    gload16(gB + k0 + 32, lB1);
    __syncthreads();
    #pragma unroll
    for (int ph = 0; ph < 2; ph++) {
      const unsigned short* Ap = ph ? As1 : As0;
      const unsigned short* Bp = ph ? Bs1 : Bs0;
      bf16x8 af[2], bfr[4];
      #pragma unroll
      for (int i = 0; i < 2; i++)
        af[i] = *(const bf16x8*)&Ap[(wave * 32 + i * 16 + l16) * 32 + quad * 8];
      #pragma unroll
      for (int i = 0; i < 4; i++)
        bfr[i] = *(const bf16x8*)&Bp[(i * 16 + l16) * 32 + quad * 8];
      #pragma unroll
      for (int mi = 0; mi < 2; mi++)
        #pragma unroll
        for (int ni = 0; ni < 4; ni++)
          acc[mi][ni] = mfma32(af[mi], bfr[ni], acc[mi][ni]);
    }
    __syncthreads();
  }

  #pragma unroll
  for (int mi = 0; mi < 2; mi++)
    #pragma unroll
    for (int ni = 0; ni < 4; ni++) {
      int col = bn + ni * 16 + l16;
      float bv = bias[col];
      #pragma unroll
      for (int r = 0; r < 4; r++) {
        int row = bm + wave * 32 + mi * 16 + quad * 4 + r;
        Cf[(size_t)row * N + col] = acc[mi][ni][r] + bv + res[(size_t)row * N + col];
      }
    }
}

// ---------------- LayerNorm over last dim (1024) ----------------------------
__global__ __launch_bounds__(256) void k_ln(const float* __restrict__ x,
                                            const float* __restrict__ g,
                                            const float* __restrict__ be,
                                            float* __restrict__ out) {
  __shared__ float red[8];
  const int row = blockIdx.x, tid = threadIdx.x;
  const float* xr = x + (size_t)row * HIDDEN;
  float4 v = ((const float4*)xr)[tid];
  float s = v.x + v.y + v.z + v.w;
  float s2 = v.x * v.x + v.y * v.y + v.z * v.z + v.w * v.w;
  #pragma unroll
  for (int off = 32; off >= 1; off >>= 1) {
    s += __shfl_xor(s, off, 64);
    s2 += __shfl_xor(s2, off, 64);
  }
  const int wave = tid >> 6, lane = tid & 63;
  if (lane == 0) { red[wave * 2] = s; red[wave * 2 + 1] = s2; }
  __syncthreads();
  float ts = red[0] + red[2] + red[4] + red[6];
  float ts2 = red[1] + red[3] + red[5] + red[7];
  float mu = ts * (1.f / HIDDEN);
  float var = ts2 * (1.f / HIDDEN) - mu * mu;
  float rs = rsqrtf(var + 1e-5f);
  float4 gv = ((const float4*)g)[tid];
  float4 bv = ((const float4*)be)[tid];
  float4 o;
  o.x = (v.x - mu) * rs * gv.x + bv.x;
  o.y = (v.y - mu) * rs * gv.y + bv.y;
  o.z = (v.z - mu) * rs * gv.z + bv.z;
  o.w = (v.w - mu) * rs * gv.w + bv.w;
  ((float4*)(out + (size_t)row * HIDDEN))[tid] = o;
}

extern "C" void kernel_launch(void* const* d_in, const int* in_sizes, int n_in,
                              void* d_out, int out_size, void* d_ws, size_t ws_size,
                              hipStream_t stream) {
  const float* hs      = (const float*)d_in[0];
  const float* w_qkv   = (const float*)d_in[1];
  const float* b_qkv   = (const float*)d_in[2];
  const float* w_dense = (const float*)d_in[3];
  const float* b_dense = (const float*)d_in[4];
  const float* ln_g    = (const float*)d_in[5];
  const float* ln_b    = (const float*)d_in[6];
  float* out = (float*)d_out;

  // ws map (53.0 MB):
  char* ws = (char*)d_ws;
  unsigned short* Xb  = (unsigned short*)(ws + 0);
  unsigned short* Wqt = (unsigned short*)(ws + 8388608);
  unsigned short* Qg  = (unsigned short*)(ws + 16777216);
  float* Xr           = (float*)(ws + 16777216);           // over dead Qg/Kg
  unsigned short* Kg  = (unsigned short*)(ws + 25165824);
  unsigned short* Vg  = (unsigned short*)(ws + 33554432);
  unsigned short* Ctx = (unsigned short*)(ws + 41943040);
  unsigned short* Wdt = (unsigned short*)(ws + 50855936);

  k_prep<<<8192, 256, 0, stream>>>(hs, Xb, w_qkv, Wqt, w_dense, Wdt);
  k_gemm_qkv<<<dim3(24, 32), 256, 0, stream>>>(Xb, Wqt, b_qkv, Qg, Kg, Vg);
  k_attn<<<512, 256, 0, stream>>>(Qg, Kg, Vg, Ctx);
  k_gemm_dense<<<dim3(16, 32), 256, 0, stream>>>(Ctx, Wdt, b_dense, hs, Xr);
  k_ln<<<4096, 256, 0, stream>>>(Xr, ln_g, ln_b, out);
}